// Round 2
// baseline (397.342 us; speedup 1.0000x reference)
//
#include <hip/hip_runtime.h>
#include <math.h>

// Problem dims: T=4, B=32, C=512, H=W=16 -> N=256, heads=8, Ch=64
// d_out = [out: (T,B,C,H,W) f32 = 16,777,216][v: (T,B,8,256,64) f32 = 16,777,216]

typedef __bf16 bf16x8 __attribute__((ext_vector_type(8)));
typedef float f32x4 __attribute__((ext_vector_type(4)));

// workspace layout (bytes)
#define OFF_WB  0u           // 4 * 512*512 bf16 = 2 MB   (gate,q,k,proj)
#define OFF_SS  2097152u     // 4 * 1024 f32 (scale[512], shift[512] per set)
#define OFF_XS  2113536u     // xs  spikes bf16 [t,b,n,c]  33.5 MB
#define OFF_GS  35667968u    // gate spikes bf16 [t,b,n,c] 33.5 MB
#define OFF_QS  69222400u    // q   spikes bf16 [t,b,n,c]  33.5 MB
#define OFF_KV  102776832u   // kv  spikes bf16 [t,b,c]    128 KB

__device__ __forceinline__ unsigned short f2bf(float f) {
  unsigned u = __float_as_uint(f);
  u += 0x7fffu + ((u >> 16) & 1u);
  return (unsigned short)(u >> 16);
}

struct PrepParams {
  const float* W[4];
  const float* bias2[2];            // gate_b, proj_b
  const float* g[4]; const float* be[4]; const float* m[4]; const float* v[4];
};

// ---------------- prep: W f32->bf16, fold BN (+bias) into scale/shift ----------------
__global__ __launch_bounds__(256) void prep_kernel(PrepParams p, unsigned char* __restrict__ ws) {
  int w = blockIdx.x, o = blockIdx.y;
  const float* Ws = p.W[w];
  unsigned short* Wb = (unsigned short*)(ws + OFF_WB) + (size_t)w * 262144;
  for (int c = threadIdx.x; c < 512; c += 256)
    Wb[o * 512 + c] = f2bf(Ws[o * 512 + c]);
  if (threadIdx.x == 0) {
    float g = p.g[w][o], be = p.be[w][o], mm = p.m[w][o], vv = p.v[w][o];
    float rs = 1.0f / sqrtf(vv + 1e-5f);
    float scale = g * rs;
    float bias = (w == 0) ? p.bias2[0][o] : ((w == 3) ? p.bias2[1][o] : 0.0f);
    float* ss = (float*)(ws + OFF_SS) + w * 1024;
    ss[o] = scale;
    ss[512 + o] = be - g * mm * rs + scale * bias;
  }
}

// ---------------- first LIF (exact f32) + transpose to xs[t,b,n,c] bf16 ----------------
__global__ __launch_bounds__(256) void lif1_kernel(const float* __restrict__ x,
                                                   unsigned char* __restrict__ ws) {
  __shared__ unsigned short sp[4][32][65];
  int tid = threadIdx.x;
  int b = blockIdx.z, c0 = blockIdx.y * 32, n0 = blockIdx.x * 64;
  int nl = tid & 63, cb = tid >> 6;
#pragma unroll
  for (int g = 0; g < 8; ++g) {
    int cl = cb + g * 4;                       // 0..31
    size_t base = ((size_t)b * 512 + (size_t)(c0 + cl)) * 256 + n0 + nl;
    float v = 0.f;
#pragma unroll
    for (int t = 0; t < 4; ++t) {
      float xv = x[base + (size_t)t * 4194304];
      v += (xv - v) * 0.5f;                    // v += (x - v)/TAU, TAU=2
      bool s = (v >= 1.f);
      v = s ? 0.f : v;
      sp[t][cl][nl] = s ? 0x3f80 : 0;
    }
  }
  __syncthreads();
  unsigned short* xs = (unsigned short*)(ws + OFF_XS);
#pragma unroll
  for (int it = 0; it < 2; ++it) {
    int s = it * 256 + tid;                    // 0..511
    int half = s & 1, n_l = (s >> 1) & 63, t = s >> 7;
    union { unsigned short u[16]; uint4 q[2]; } pk;
#pragma unroll
    for (int j = 0; j < 16; ++j) pk.u[j] = sp[t][half * 16 + j][n_l];
    size_t off = ((size_t)(t * 32 + b) * 256 + (size_t)(n0 + n_l)) * 512 + c0 + half * 16;
    *(uint4*)(xs + off) = pk.q[0];
    *(uint4*)(xs + off + 8) = pk.q[1];
  }
}

// ---------------- triple GEMM (gate/q/k) + BN + fused LIF over t ----------------
// grid: x = n-tile (4 x 64), y = o-tile (4 x 128), z = w*32 + b  (w: 0=gate,1=q,2=k)
__global__ __launch_bounds__(256, 2) void gemm3_kernel(unsigned char* __restrict__ ws,
                                                       float* __restrict__ vout) {
  __shared__ __align__(16) unsigned short lA[128 * 72];
  __shared__ __align__(16) unsigned short lB[64 * 72];
  __shared__ unsigned short lT[128 * 65];
  int tid = threadIdx.x;
  int w = blockIdx.z >> 5, b = blockIdx.z & 31;
  int o0 = blockIdx.y * 128, n0 = blockIdx.x * 64;
  int lane = tid & 63, wid = tid >> 6;
  int wm = (wid >> 1) * 64, wn = (wid & 1) * 32;
  const unsigned short* Wb = (const unsigned short*)(ws + OFF_WB) + (size_t)w * 262144;
  const unsigned short* xs = (const unsigned short*)(ws + OFF_XS);
  const float* ss = (const float*)(ws + OFF_SS) + w * 1024;
  unsigned short* spout = (w == 0) ? (unsigned short*)(ws + OFF_GS)
                                   : (unsigned short*)(ws + OFF_QS);

  float vstate[4][2][4];
#pragma unroll
  for (int mf = 0; mf < 4; ++mf)
#pragma unroll
    for (int nf = 0; nf < 2; ++nf)
#pragma unroll
      for (int r = 0; r < 4; ++r) vstate[mf][nf][r] = 0.f;

  for (int t = 0; t < 4; ++t) {
    f32x4 acc[4][2];
#pragma unroll
    for (int mf = 0; mf < 4; ++mf)
#pragma unroll
      for (int nf = 0; nf < 2; ++nf) acc[mf][nf] = (f32x4){0.f, 0.f, 0.f, 0.f};
    const unsigned short* xrow = xs + ((size_t)(t * 32 + b) * 256 + n0) * 512;

    for (int ks = 0; ks < 8; ++ks) {
      __syncthreads();
#pragma unroll
      for (int i = 0; i < 4; ++i) {            // stage W tile 128x64
        int s = i * 256 + tid;
        int r = s >> 3, kc = (s & 7) * 8;
        *(uint4*)&lA[r * 72 + kc] =
            *(const uint4*)(Wb + (size_t)(o0 + r) * 512 + ks * 64 + kc);
      }
#pragma unroll
      for (int i = 0; i < 2; ++i) {            // stage xs tile [n][k] 64x64
        int s = i * 256 + tid;
        int r = s >> 3, kc = (s & 7) * 8;
        *(uint4*)&lB[r * 72 + kc] =
            *(const uint4*)(xrow + (size_t)r * 512 + ks * 64 + kc);
      }
      __syncthreads();
#pragma unroll
      for (int ksub = 0; ksub < 2; ++ksub) {
        int kof = ksub * 32 + (lane >> 4) * 8;
        bf16x8 af[4], bfr[2];
#pragma unroll
        for (int mf = 0; mf < 4; ++mf)
          af[mf] = *(const bf16x8*)&lA[(wm + mf * 16 + (lane & 15)) * 72 + kof];
#pragma unroll
        for (int nf = 0; nf < 2; ++nf)
          bfr[nf] = *(const bf16x8*)&lB[(wn + nf * 16 + (lane & 15)) * 72 + kof];
#pragma unroll
        for (int mf = 0; mf < 4; ++mf)
#pragma unroll
          for (int nf = 0; nf < 2; ++nf)
            acc[mf][nf] = __builtin_amdgcn_mfma_f32_16x16x32_bf16(
                af[mf], bfr[nf], acc[mf][nf], 0, 0, 0);
      }
    }
    __syncthreads();
    // BN + LIF, stash spikes [o][n] in LDS
#pragma unroll
    for (int mf = 0; mf < 4; ++mf)
#pragma unroll
      for (int nf = 0; nf < 2; ++nf)
#pragma unroll
        for (int r = 0; r < 4; ++r) {
          int ol = wm + mf * 16 + (lane >> 4) * 4 + r;
          int nn = wn + nf * 16 + (lane & 15);
          int o = o0 + ol;
          float val = acc[mf][nf][r] * ss[o] + ss[512 + o];
          float vs = vstate[mf][nf][r];
          vs += (val - vs) * 0.5f;
          bool s = (vs >= 1.f);
          vstate[mf][nf][r] = s ? 0.f : vs;
          lT[ol * 65 + nn] = s ? 0x3f80 : 0;
        }
    __syncthreads();
    if (w < 2) {                               // gate/q -> ws [t,b,n,c] bf16
#pragma unroll
      for (int it = 0; it < 2; ++it) {
        int s = it * 256 + tid;
        int n_l = s >> 3, oc = (s & 7) * 16;
        union { unsigned short u[16]; uint4 q[2]; } pk;
#pragma unroll
        for (int j = 0; j < 16; ++j) pk.u[j] = lT[(oc + j) * 65 + n_l];
        size_t off = ((size_t)(t * 32 + b) * 256 + (size_t)(n0 + n_l)) * 512 + o0 + oc;
        *(uint4*)(spout + off) = pk.q[0];
        *(uint4*)(spout + off + 8) = pk.q[1];
      }
    } else {                                   // k -> v output f32 (T,B,8,N,64)
#pragma unroll
      for (int it = 0; it < 4; ++it) {
        int s = it * 256 + tid;
        int n_l = s >> 4, oc = (s & 15) * 8;
        int o = o0 + oc;
        int h = o >> 6, ch = o & 63;
        float4 f0, f1;
        f0.x = lT[(oc + 0) * 65 + n_l] ? 1.f : 0.f;
        f0.y = lT[(oc + 1) * 65 + n_l] ? 1.f : 0.f;
        f0.z = lT[(oc + 2) * 65 + n_l] ? 1.f : 0.f;
        f0.w = lT[(oc + 3) * 65 + n_l] ? 1.f : 0.f;
        f1.x = lT[(oc + 4) * 65 + n_l] ? 1.f : 0.f;
        f1.y = lT[(oc + 5) * 65 + n_l] ? 1.f : 0.f;
        f1.z = lT[(oc + 6) * 65 + n_l] ? 1.f : 0.f;
        f1.w = lT[(oc + 7) * 65 + n_l] ? 1.f : 0.f;
        size_t off = (((size_t)(t * 32 + b) * 8 + h) * 256 + (size_t)(n0 + n_l)) * 64 + ch;
        *(float4*)(vout + off) = f0;
        *(float4*)(vout + off + 4) = f1;
      }
    }
  }
}

// ---------------- kv = lif(sum_n k*v, v_th=0.5)  (k*v = k since spikes) ----------------
// grid: 256 blocks = (b, head) ; 256 threads = 64 ch x 4 n-groups
__global__ __launch_bounds__(256) void kv_kernel(const float* __restrict__ vout,
                                                 unsigned char* __restrict__ ws) {
  __shared__ float red[4][64];
  int tid = threadIdx.x;
  int b = blockIdx.x >> 3, hb = blockIdx.x & 7;
  int ch = tid & 63, ng = tid >> 6;
  unsigned short* kvs = (unsigned short*)(ws + OFF_KV);
  float vm = 0.f;
  for (int t = 0; t < 4; ++t) {
    size_t base = (((size_t)(t * 32 + b) * 8 + hb) * 256 + (size_t)ng * 64) * 64 + ch;
    float sum = 0.f;
#pragma unroll 8
    for (int i = 0; i < 64; ++i) sum += vout[base + (size_t)i * 64];
    red[ng][ch] = sum;
    __syncthreads();
    if (ng == 0) {
      float tot = red[0][ch] + red[1][ch] + red[2][ch] + red[3][ch];
      vm += (tot - vm) * 0.5f;
      bool s = (vm >= 0.5f);
      vm = s ? 0.f : vm;
      kvs[(size_t)(t * 32 + b) * 512 + hb * 64 + ch] = s ? 0x3f80 : 0;
    }
    __syncthreads();
  }
}

// ---------------- proj GEMM on a = q&gate&kv, BN + residual ----------------
// grid: x = n-tile (2 x 128), y = o-tile (4 x 128), z = t*32+b
__global__ __launch_bounds__(256, 2) void proj_kernel(const unsigned char* __restrict__ ws,
                                                      const float* __restrict__ x,
                                                      float* __restrict__ out) {
  __shared__ __align__(16) unsigned short lA[128 * 72];
  __shared__ __align__(16) unsigned short lB[128 * 72];
  int tid = threadIdx.x;
  int t = blockIdx.z >> 5, b = blockIdx.z & 31;
  int o0 = blockIdx.y * 128, n0 = blockIdx.x * 128;
  int lane = tid & 63, wid = tid >> 6;
  int wm = (wid >> 1) * 64, wn = (wid & 1) * 64;
  const unsigned short* Wb = (const unsigned short*)(ws + OFF_WB) + (size_t)3 * 262144;
  const unsigned short* qs =
      (const unsigned short*)(ws + OFF_QS) + ((size_t)(t * 32 + b) * 256 + n0) * 512;
  const unsigned short* gs =
      (const unsigned short*)(ws + OFF_GS) + ((size_t)(t * 32 + b) * 256 + n0) * 512;
  const unsigned short* kvp =
      (const unsigned short*)(ws + OFF_KV) + (size_t)(t * 32 + b) * 512;
  const float* ss = (const float*)(ws + OFF_SS) + 3 * 1024;

  f32x4 acc[4][4];
#pragma unroll
  for (int mf = 0; mf < 4; ++mf)
#pragma unroll
    for (int nf = 0; nf < 4; ++nf) acc[mf][nf] = (f32x4){0.f, 0.f, 0.f, 0.f};

  for (int ks = 0; ks < 8; ++ks) {
    __syncthreads();
#pragma unroll
    for (int i = 0; i < 4; ++i) {              // stage proj W tile 128x64
      int s = i * 256 + tid;
      int r = s >> 3, kc = (s & 7) * 8;
      *(uint4*)&lA[r * 72 + kc] =
          *(const uint4*)(Wb + (size_t)(o0 + r) * 512 + ks * 64 + kc);
    }
#pragma unroll
    for (int i = 0; i < 4; ++i) {              // stage a = q & gate & kv, [n][k]
      int s = i * 256 + tid;
      int r = s >> 3, kc = (s & 7) * 8;
      size_t e = (size_t)r * 512 + ks * 64 + kc;
      uint4 qv = *(const uint4*)(qs + e);
      uint4 gv = *(const uint4*)(gs + e);
      uint4 kvv = *(const uint4*)(kvp + ks * 64 + kc);
      uint4 av;
      av.x = qv.x & gv.x & kvv.x;
      av.y = qv.y & gv.y & kvv.y;
      av.z = qv.z & gv.z & kvv.z;
      av.w = qv.w & gv.w & kvv.w;
      *(uint4*)&lB[r * 72 + kc] = av;
    }
    __syncthreads();
#pragma unroll
    for (int ksub = 0; ksub < 2; ++ksub) {
      int kof = ksub * 32 + (lane >> 4) * 8;
      bf16x8 af[4], bfr[4];
#pragma unroll
      for (int mf = 0; mf < 4; ++mf)
        af[mf] = *(const bf16x8*)&lA[(wm + mf * 16 + (lane & 15)) * 72 + kof];
#pragma unroll
      for (int nf = 0; nf < 4; ++nf)
        bfr[nf] = *(const bf16x8*)&lB[(wn + nf * 16 + (lane & 15)) * 72 + kof];
#pragma unroll
      for (int mf = 0; mf < 4; ++mf)
#pragma unroll
        for (int nf = 0; nf < 4; ++nf)
          acc[mf][nf] = __builtin_amdgcn_mfma_f32_16x16x32_bf16(
              af[mf], bfr[nf], acc[mf][nf], 0, 0, 0);
    }
  }
  // epilogue: BN + residual
#pragma unroll
  for (int mf = 0; mf < 4; ++mf)
#pragma unroll
    for (int r = 0; r < 4; ++r) {
      int o = o0 + wm + mf * 16 + (lane >> 4) * 4 + r;
      float scale = ss[o], shift = ss[512 + o];
#pragma unroll
      for (int nf = 0; nf < 4; ++nf) {
        int nn = n0 + wn + nf * 16 + (lane & 15);
        size_t idx = ((size_t)(t * 32 + b) * 512 + o) * 256 + nn;
        out[idx] = acc[mf][nf][r] * scale + shift + x[idx];
      }
    }
}

extern "C" void kernel_launch(void* const* d_in, const int* in_sizes, int n_in,
                              void* d_out, int out_size, void* d_ws, size_t ws_size,
                              hipStream_t stream) {
  const float* x = (const float*)d_in[0];
  unsigned char* ws = (unsigned char*)d_ws;
  float* out = (float*)d_out;
  float* vout = out + 16777216;

  PrepParams p;
  p.W[0] = (const float*)d_in[1];   // gate_w
  p.W[1] = (const float*)d_in[3];   // q_w
  p.W[2] = (const float*)d_in[4];   // k_w
  p.W[3] = (const float*)d_in[5];   // proj_w
  p.bias2[0] = (const float*)d_in[2];  // gate_b
  p.bias2[1] = (const float*)d_in[6];  // proj_b
  const int bni[4] = {7, 11, 15, 19};  // gate,q,k,proj BN base indices
  for (int w = 0; w < 4; ++w) {
    p.g[w]  = (const float*)d_in[bni[w] + 0];
    p.be[w] = (const float*)d_in[bni[w] + 1];
    p.m[w]  = (const float*)d_in[bni[w] + 2];
    p.v[w]  = (const float*)d_in[bni[w] + 3];
  }

  prep_kernel<<<dim3(4, 512), dim3(256), 0, stream>>>(p, ws);
  lif1_kernel<<<dim3(4, 16, 32), dim3(256), 0, stream>>>(x, ws);
  gemm3_kernel<<<dim3(4, 4, 96), dim3(256), 0, stream>>>(ws, vout);
  kv_kernel<<<dim3(256), dim3(256), 0, stream>>>(vout, ws);
  proj_kernel<<<dim3(2, 4, 128), dim3(256), 0, stream>>>(ws, x, out);
}

// Round 3
// 370.043 us; speedup vs baseline: 1.0738x; 1.0738x over previous
//
#include <hip/hip_runtime.h>
#include <math.h>

// Problem dims: T=4, B=32, C=512, H=W=16 -> N=256, heads=8, Ch=64
// d_out = [out: (T,B,C,H,W) f32 = 16,777,216][v: (T,B,8,256,64) f32 = 16,777,216]

typedef __bf16 bf16x8 __attribute__((ext_vector_type(8)));
typedef float f32x4 __attribute__((ext_vector_type(4)));

// workspace layout (bytes)
#define OFF_WB    0u           // 4 * 512*512 bf16 = 2 MB   (gate,q,k,proj)
#define OFF_SS    2097152u     // 4 * 1024 f32 (scale[512], shift[512] per set)
#define OFF_XS    2113536u     // xs  spikes bf16 [t,b,n,c]  33.5 MB
#define OFF_GS    35667968u    // gate spikes bf16 [t,b,n,c] 33.5 MB
#define OFF_QS    69222400u    // q   spikes bf16 [t,b,n,c]  33.5 MB
#define OFF_KV    102776832u   // kv  spikes bf16 [t,b,c]    128 KB
#define OFF_KVACC 102907904u   // kv n-count partials f32 [t,b,ntile,c] 1 MB

__device__ __forceinline__ unsigned short f2bf(float f) {
  unsigned u = __float_as_uint(f);
  u += 0x7fffu + ((u >> 16) & 1u);
  return (unsigned short)(u >> 16);
}

// async global->LDS, 16B per lane; LDS dest = base + lane*16 (wave-uniform base)
__device__ __forceinline__ void gload16(const void* g, void* l) {
  __builtin_amdgcn_global_load_lds(
      (const __attribute__((address_space(1))) void*)g,
      (__attribute__((address_space(3))) void*)l, 16, 0, 0);
}

struct PrepParams {
  const float* W[4];
  const float* bias2[2];            // gate_b, proj_b
  const float* g[4]; const float* be[4]; const float* m[4]; const float* v[4];
};

// ---------------- prep: W f32->bf16, fold BN (+bias) into scale/shift ----------------
__global__ __launch_bounds__(256) void prep_kernel(PrepParams p, unsigned char* __restrict__ ws) {
  int w = blockIdx.x, o = blockIdx.y;
  const float* Ws = p.W[w];
  unsigned short* Wb = (unsigned short*)(ws + OFF_WB) + (size_t)w * 262144;
  for (int c = threadIdx.x; c < 512; c += 256)
    Wb[o * 512 + c] = f2bf(Ws[o * 512 + c]);
  if (threadIdx.x == 0) {
    float g = p.g[w][o], be = p.be[w][o], mm = p.m[w][o], vv = p.v[w][o];
    float rs = 1.0f / sqrtf(vv + 1e-5f);
    float scale = g * rs;
    float bias = (w == 0) ? p.bias2[0][o] : ((w == 3) ? p.bias2[1][o] : 0.0f);
    float* ss = (float*)(ws + OFF_SS) + w * 1024;
    ss[o] = scale;
    ss[512 + o] = be - g * mm * rs + scale * bias;
  }
}

// ---------------- first LIF (exact f32) + transpose to xs[t,b,n,c] bf16 ----------------
__global__ __launch_bounds__(256) void lif1_kernel(const float* __restrict__ x,
                                                   unsigned char* __restrict__ ws) {
  __shared__ unsigned short sp[4][32][65];
  int tid = threadIdx.x;
  int b = blockIdx.z, c0 = blockIdx.y * 32, n0 = blockIdx.x * 64;
  int nl = tid & 63, cb = tid >> 6;
#pragma unroll
  for (int g = 0; g < 8; ++g) {
    int cl = cb + g * 4;                       // 0..31
    size_t base = ((size_t)b * 512 + (size_t)(c0 + cl)) * 256 + n0 + nl;
    float v = 0.f;
#pragma unroll
    for (int t = 0; t < 4; ++t) {
      float xv = x[base + (size_t)t * 4194304];
      v += (xv - v) * 0.5f;                    // v += (x - v)/TAU, TAU=2
      bool s = (v >= 1.f);
      v = s ? 0.f : v;
      sp[t][cl][nl] = s ? 0x3f80 : 0;
    }
  }
  __syncthreads();
  unsigned short* xs = (unsigned short*)(ws + OFF_XS);
#pragma unroll
  for (int it = 0; it < 2; ++it) {
    int s = it * 256 + tid;                    // 0..511
    int half = s & 1, n_l = (s >> 1) & 63, t = s >> 7;
    union { unsigned short u[16]; uint4 q[2]; } pk;
#pragma unroll
    for (int j = 0; j < 16; ++j) pk.u[j] = sp[t][half * 16 + j][n_l];
    size_t off = ((size_t)(t * 32 + b) * 256 + (size_t)(n0 + n_l)) * 512 + c0 + half * 16;
    *(uint4*)(xs + off) = pk.q[0];
    *(uint4*)(xs + off + 8) = pk.q[1];
  }
}

// ---------------- triple GEMM (gate/q/k) + BN + fused LIF over t ----------------
// grid: x = n-tile (4 x 64), y = o-tile (4 x 128), z = w*32 + b  (w: 0=gate,1=q,2=k)
// Staging via global_load_lds, linear LDS, XOR-swizzle carried by the global src
// address (rule #21: swizzled source + swizzled read, linear dest).
__global__ __launch_bounds__(256, 3) void gemm3_kernel(unsigned char* __restrict__ ws,
                                                       float* __restrict__ vout,
                                                       float* __restrict__ kvacc) {
  __shared__ __align__(16) unsigned short lA[128 * 64];
  __shared__ __align__(16) unsigned short lB[64 * 64];
  __shared__ unsigned short lT[128 * 65];
  int tid = threadIdx.x;
  int w = blockIdx.z >> 5, b = blockIdx.z & 31;
  int o0 = blockIdx.y * 128, n0 = blockIdx.x * 64;
  int lane = tid & 63, wid = tid >> 6;
  int wm = (wid >> 1) * 64, wn = (wid & 1) * 32;
  int l8 = lane >> 3, l7 = lane & 7;
  int swzk = (l7 ^ l8) << 3;                   // swizzled k-offset (elements) for staging
  int fr = lane & 15, fhi = lane >> 4;
  int swzf = (lane & 7) << 3;                  // XOR for fragment reads
  const unsigned short* Wb = (const unsigned short*)(ws + OFF_WB) + (size_t)w * 262144;
  const unsigned short* xs = (const unsigned short*)(ws + OFF_XS);
  const float* ss = (const float*)(ws + OFF_SS) + w * 1024;
  unsigned short* spout = (w == 0) ? (unsigned short*)(ws + OFF_GS)
                                   : (unsigned short*)(ws + OFF_QS);

  float vstate[4][2][4];
#pragma unroll
  for (int mf = 0; mf < 4; ++mf)
#pragma unroll
    for (int nf = 0; nf < 2; ++nf)
#pragma unroll
      for (int r = 0; r < 4; ++r) vstate[mf][nf][r] = 0.f;

  for (int t = 0; t < 4; ++t) {
    f32x4 acc[4][2];
#pragma unroll
    for (int mf = 0; mf < 4; ++mf)
#pragma unroll
      for (int nf = 0; nf < 2; ++nf) acc[mf][nf] = (f32x4){0.f, 0.f, 0.f, 0.f};
    const unsigned short* xrow = xs + ((size_t)(t * 32 + b) * 256 + n0) * 512;

    for (int ks = 0; ks < 8; ++ks) {
      __syncthreads();
#pragma unroll
      for (int i = 0; i < 4; ++i) {            // W tile 128x64 -> lA (linear, src-swizzled)
        int r = wid * 32 + i * 8 + l8;
        gload16(Wb + (size_t)(o0 + r) * 512 + ks * 64 + swzk, lA + wid * 2048 + i * 512);
      }
#pragma unroll
      for (int i = 0; i < 2; ++i) {            // xs tile 64x64 -> lB
        int r = wid * 16 + i * 8 + l8;
        gload16(xrow + (size_t)r * 512 + ks * 64 + swzk, lB + wid * 1024 + i * 512);
      }
      __syncthreads();
#pragma unroll
      for (int ksub = 0; ksub < 2; ++ksub) {
        int kof = (ksub * 32 + fhi * 8) ^ swzf;
        bf16x8 af[4], bfr[2];
#pragma unroll
        for (int mf = 0; mf < 4; ++mf)
          af[mf] = *(const bf16x8*)&lA[(wm + mf * 16 + fr) * 64 + kof];
#pragma unroll
        for (int nf = 0; nf < 2; ++nf)
          bfr[nf] = *(const bf16x8*)&lB[(wn + nf * 16 + fr) * 64 + kof];
#pragma unroll
        for (int mf = 0; mf < 4; ++mf)
#pragma unroll
          for (int nf = 0; nf < 2; ++nf)
            acc[mf][nf] = __builtin_amdgcn_mfma_f32_16x16x32_bf16(
                af[mf], bfr[nf], acc[mf][nf], 0, 0, 0);
      }
    }
    __syncthreads();
    // BN + LIF, stash spikes [o][n] in LDS
#pragma unroll
    for (int mf = 0; mf < 4; ++mf)
#pragma unroll
      for (int nf = 0; nf < 2; ++nf)
#pragma unroll
        for (int r = 0; r < 4; ++r) {
          int ol = wm + mf * 16 + (lane >> 4) * 4 + r;
          int nn = wn + nf * 16 + (lane & 15);
          int o = o0 + ol;
          float val = acc[mf][nf][r] * ss[o] + ss[512 + o];
          float vs = vstate[mf][nf][r];
          vs += (val - vs) * 0.5f;
          bool s = (vs >= 1.f);
          vstate[mf][nf][r] = s ? 0.f : vs;
          lT[ol * 65 + nn] = s ? 0x3f80 : 0;
        }
    __syncthreads();
    if (w < 2) {                               // gate/q -> ws [t,b,n,c] bf16
#pragma unroll
      for (int it = 0; it < 2; ++it) {
        int s = it * 256 + tid;
        int n_l = s >> 3, oc = (s & 7) * 16;
        union { unsigned short u[16]; uint4 q[2]; } pk;
#pragma unroll
        for (int j = 0; j < 16; ++j) pk.u[j] = lT[(oc + j) * 65 + n_l];
        size_t off = ((size_t)(t * 32 + b) * 256 + (size_t)(n0 + n_l)) * 512 + o0 + oc;
        *(uint4*)(spout + off) = pk.q[0];
        *(uint4*)(spout + off + 8) = pk.q[1];
      }
    } else {                                   // k -> v output f32 (T,B,8,N,64)
#pragma unroll
      for (int it = 0; it < 4; ++it) {
        int s = it * 256 + tid;
        int n_l = s >> 4, oc = (s & 15) * 8;
        int o = o0 + oc;
        int h = o >> 6, ch = o & 63;
        float4 f0, f1;
        f0.x = lT[(oc + 0) * 65 + n_l] ? 1.f : 0.f;
        f0.y = lT[(oc + 1) * 65 + n_l] ? 1.f : 0.f;
        f0.z = lT[(oc + 2) * 65 + n_l] ? 1.f : 0.f;
        f0.w = lT[(oc + 3) * 65 + n_l] ? 1.f : 0.f;
        f1.x = lT[(oc + 4) * 65 + n_l] ? 1.f : 0.f;
        f1.y = lT[(oc + 5) * 65 + n_l] ? 1.f : 0.f;
        f1.z = lT[(oc + 6) * 65 + n_l] ? 1.f : 0.f;
        f1.w = lT[(oc + 7) * 65 + n_l] ? 1.f : 0.f;
        size_t off = (((size_t)(t * 32 + b) * 8 + h) * 256 + (size_t)(n0 + n_l)) * 64 + ch;
        *(float4*)(vout + off) = f0;
        *(float4*)(vout + off + 4) = f1;
      }
      // per-block n-count partials for kv (integer-exact): 2 threads per o row
      {
        int o = tid >> 1, nh = (tid & 1) * 32;
        int cnt = 0;
#pragma unroll
        for (int n = 0; n < 32; ++n) cnt += (lT[o * 65 + nh + n] ? 1 : 0);
        cnt += __shfl_xor(cnt, 1);
        if ((tid & 1) == 0)
          kvacc[((size_t)(t * 32 + b) * 4 + blockIdx.x) * 512 + o0 + o] = (float)cnt;
      }
    }
  }
}

// ---------------- kv = lif(sum_n k, v_th=0.5) from 1MB partials ----------------
// grid: 32 blocks = b ; 256 threads, 2 channels each
__global__ __launch_bounds__(256) void kv_kernel(const float* __restrict__ kvacc,
                                                 unsigned char* __restrict__ ws) {
  int b = blockIdx.x;
  unsigned short* kvs = (unsigned short*)(ws + OFF_KV);
#pragma unroll
  for (int j = 0; j < 2; ++j) {
    int c = j * 256 + threadIdx.x;
    float vm = 0.f;
#pragma unroll
    for (int t = 0; t < 4; ++t) {
      const float* p = kvacc + (size_t)(t * 32 + b) * 2048 + c;
      float tot = p[0] + p[512] + p[1024] + p[1536];
      vm += (tot - vm) * 0.5f;
      bool s = (vm >= 0.5f);
      vm = s ? 0.f : vm;
      kvs[(size_t)(t * 32 + b) * 512 + c] = s ? 0x3f80 : 0;
    }
  }
}

// ---------------- proj GEMM on a = q&gate&kv, BN + residual ----------------
// grid: x = n-tile (2 x 128), y = o-tile (4 x 128), z = t*32+b
__global__ __launch_bounds__(256, 3) void proj_kernel(const unsigned char* __restrict__ ws,
                                                      const float* __restrict__ x,
                                                      float* __restrict__ out) {
  __shared__ __align__(16) unsigned short lA[128 * 64];
  __shared__ __align__(16) unsigned short lB[128 * 72];
  int tid = threadIdx.x;
  int t = blockIdx.z >> 5, b = blockIdx.z & 31;
  int o0 = blockIdx.y * 128, n0 = blockIdx.x * 128;
  int lane = tid & 63, wid = tid >> 6;
  int wm = (wid >> 1) * 64, wn = (wid & 1) * 64;
  int l8 = lane >> 3, l7 = lane & 7;
  int swzk = (l7 ^ l8) << 3;
  int fr = lane & 15, fhi = lane >> 4;
  int swzf = (lane & 7) << 3;
  const unsigned short* Wb = (const unsigned short*)(ws + OFF_WB) + (size_t)3 * 262144;
  const unsigned short* qs =
      (const unsigned short*)(ws + OFF_QS) + ((size_t)(t * 32 + b) * 256 + n0) * 512;
  const unsigned short* gs =
      (const unsigned short*)(ws + OFF_GS) + ((size_t)(t * 32 + b) * 256 + n0) * 512;
  const unsigned short* kvp =
      (const unsigned short*)(ws + OFF_KV) + (size_t)(t * 32 + b) * 512;
  const float* ss = (const float*)(ws + OFF_SS) + 3 * 1024;

  f32x4 acc[4][4];
#pragma unroll
  for (int mf = 0; mf < 4; ++mf)
#pragma unroll
    for (int nf = 0; nf < 4; ++nf) acc[mf][nf] = (f32x4){0.f, 0.f, 0.f, 0.f};

  for (int ks = 0; ks < 8; ++ks) {
    __syncthreads();
#pragma unroll
    for (int i = 0; i < 4; ++i) {              // proj W tile 128x64 -> lA (linear, src-swz)
      int r = wid * 32 + i * 8 + l8;
      gload16(Wb + (size_t)(o0 + r) * 512 + ks * 64 + swzk, lA + wid * 2048 + i * 512);
    }
#pragma unroll
    for (int i = 0; i < 4; ++i) {              // a = q & gate & kv, [n][k], padded reg-stage
      int s = i * 256 + tid;
      int r = s >> 3, kc = (s & 7) * 8;
      size_t e = (size_t)r * 512 + ks * 64 + kc;
      uint4 qv = *(const uint4*)(qs + e);
      uint4 gv = *(const uint4*)(gs + e);
      uint4 kvv = *(const uint4*)(kvp + ks * 64 + kc);
      uint4 av;
      av.x = qv.x & gv.x & kvv.x;
      av.y = qv.y & gv.y & kvv.y;
      av.z = qv.z & gv.z & kvv.z;
      av.w = qv.w & gv.w & kvv.w;
      *(uint4*)&lB[r * 72 + kc] = av;
    }
    __syncthreads();
#pragma unroll
    for (int ksub = 0; ksub < 2; ++ksub) {
      int kofA = (ksub * 32 + fhi * 8) ^ swzf;
      int kofB = ksub * 32 + fhi * 8;
      bf16x8 af[4], bfr[4];
#pragma unroll
      for (int mf = 0; mf < 4; ++mf)
        af[mf] = *(const bf16x8*)&lA[(wm + mf * 16 + fr) * 64 + kofA];
#pragma unroll
      for (int nf = 0; nf < 4; ++nf)
        bfr[nf] = *(const bf16x8*)&lB[(wn + nf * 16 + fr) * 72 + kofB];
#pragma unroll
      for (int mf = 0; mf < 4; ++mf)
#pragma unroll
        for (int nf = 0; nf < 4; ++nf)
          acc[mf][nf] = __builtin_amdgcn_mfma_f32_16x16x32_bf16(
              af[mf], bfr[nf], acc[mf][nf], 0, 0, 0);
    }
  }
  // epilogue: BN + residual
#pragma unroll
  for (int mf = 0; mf < 4; ++mf)
#pragma unroll
    for (int r = 0; r < 4; ++r) {
      int o = o0 + wm + mf * 16 + (lane >> 4) * 4 + r;
      float scale = ss[o], shift = ss[512 + o];
#pragma unroll
      for (int nf = 0; nf < 4; ++nf) {
        int nn = n0 + wn + nf * 16 + (lane & 15);
        size_t idx = ((size_t)(t * 32 + b) * 512 + o) * 256 + nn;
        out[idx] = acc[mf][nf][r] * scale + shift + x[idx];
      }
    }
}

extern "C" void kernel_launch(void* const* d_in, const int* in_sizes, int n_in,
                              void* d_out, int out_size, void* d_ws, size_t ws_size,
                              hipStream_t stream) {
  const float* x = (const float*)d_in[0];
  unsigned char* ws = (unsigned char*)d_ws;
  float* out = (float*)d_out;
  float* vout = out + 16777216;
  float* kvacc = (float*)(ws + OFF_KVACC);

  PrepParams p;
  p.W[0] = (const float*)d_in[1];   // gate_w
  p.W[1] = (const float*)d_in[3];   // q_w
  p.W[2] = (const float*)d_in[4];   // k_w
  p.W[3] = (const float*)d_in[5];   // proj_w
  p.bias2[0] = (const float*)d_in[2];  // gate_b
  p.bias2[1] = (const float*)d_in[6];  // proj_b
  const int bni[4] = {7, 11, 15, 19};  // gate,q,k,proj BN base indices
  for (int w = 0; w < 4; ++w) {
    p.g[w]  = (const float*)d_in[bni[w] + 0];
    p.be[w] = (const float*)d_in[bni[w] + 1];
    p.m[w]  = (const float*)d_in[bni[w] + 2];
    p.v[w]  = (const float*)d_in[bni[w] + 3];
  }

  prep_kernel<<<dim3(4, 512), dim3(256), 0, stream>>>(p, ws);
  lif1_kernel<<<dim3(4, 16, 32), dim3(256), 0, stream>>>(x, ws);
  gemm3_kernel<<<dim3(4, 4, 96), dim3(256), 0, stream>>>(ws, vout, kvacc);
  kv_kernel<<<dim3(32), dim3(256), 0, stream>>>(kvacc, ws);
  proj_kernel<<<dim3(2, 4, 128), dim3(256), 0, stream>>>(ws, x, out);
}